// Round 1
// baseline (8598.485 us; speedup 1.0000x reference)
//
#include <hip/hip_runtime.h>
#include <stddef.h>

#define KTAPS 125

// -------- SubM conv: out[n,co] = sum_{k valid} sum_ci fin[nbr[n,k],ci] * w[k,ci,co]
// Tile: 32 rows x 64 cols, 256 threads, ci staged in chunks of 16.
// Output-stationary (no races); whole-tile tap skip via __syncthreads_or.
__global__ __launch_bounds__(256) void subm_conv(
    const float* __restrict__ fin, const int* __restrict__ nbr,
    const float* __restrict__ w, float* __restrict__ fout,
    int N, int Cin, int Cout)
{
    const int BM = 32, BN = 64, CK = 16;
    __shared__ int   nb[BM];
    __shared__ float G[CK][BM + 2];   // +2 pad: conflict-free staging, 8B-aligned float2 reads
    __shared__ float W[CK][BN];

    int tid  = threadIdx.x;
    int row0 = blockIdx.x * BM;
    int co0  = blockIdx.y * BN;

    int r2 = (tid >> 4) * 2;     // row pair   0..30
    int c4 = (tid & 15) * 4;     // col quad   0..60

    float acc[2][4] = {};

    for (int k = 0; k < KTAPS; ++k) {
        int v = -1;
        if (tid < BM) {
            int r = row0 + tid;
            if (r < N) v = nbr[(size_t)r * KTAPS + k];
            nb[tid] = v;
        }
        if (!__syncthreads_or(v >= 0)) continue;

        for (int ci0 = 0; ci0 < Cin; ci0 += CK) {
            // stage G: 32 rows x 16 ci (2 elems/thread, coalesced over ci)
            #pragma unroll
            for (int rep = 0; rep < (BM * CK) / 256; ++rep) {
                int idx = tid + rep * 256;
                int ci  = idx & (CK - 1);
                int rr  = idx >> 4;
                int src = nb[rr];
                int c   = ci0 + ci;
                float val = 0.f;
                if (src >= 0 && c < Cin) val = fin[(size_t)src * Cin + c];
                G[ci][rr] = val;
            }
            // stage W: 16 ci x 64 co (float4/thread, coalesced over co)
            {
                int ci = tid >> 4;
                int cc = (tid & 15) * 4;
                int c  = ci0 + ci;
                float4 wv = make_float4(0.f, 0.f, 0.f, 0.f);
                if (c < Cin && (co0 + cc) < Cout)
                    wv = *(const float4*)&w[((size_t)k * Cin + c) * Cout + co0 + cc];
                *(float4*)&W[ci][cc] = wv;
            }
            __syncthreads();
            #pragma unroll
            for (int ci = 0; ci < CK; ++ci) {
                float2 a = *(const float2*)&G[ci][r2];
                float4 b = *(const float4*)&W[ci][c4];
                acc[0][0] += a.x * b.x; acc[0][1] += a.x * b.y;
                acc[0][2] += a.x * b.z; acc[0][3] += a.x * b.w;
                acc[1][0] += a.y * b.x; acc[1][1] += a.y * b.y;
                acc[1][2] += a.y * b.z; acc[1][3] += a.y * b.w;
            }
            __syncthreads();
        }
    }

    #pragma unroll
    for (int i = 0; i < 2; ++i) {
        int r = row0 + r2 + i;
        if (r >= N) continue;
        if (co0 + c4 + 3 < Cout) {
            *(float4*)&fout[(size_t)r * Cout + co0 + c4] =
                make_float4(acc[i][0], acc[i][1], acc[i][2], acc[i][3]);
        } else {
            #pragma unroll
            for (int j = 0; j < 4; ++j) {
                int c = co0 + c4 + j;
                if (c < Cout) fout[(size_t)r * Cout + c] = acc[i][j];
            }
        }
    }
}

// -------- segment max pool via order-invariant monotonic-uint atomicMax (exact, deterministic)
__device__ __forceinline__ unsigned enc_f32(float f) {
    unsigned u = __float_as_uint(f);
    return (u & 0x80000000u) ? ~u : (u | 0x80000000u);
}

__global__ void pool_max(const float* __restrict__ fin, const int* __restrict__ pm,
                         unsigned* __restrict__ enc, int Nin, int C)
{
    int i = blockIdx.x * blockDim.x + threadIdx.x;
    if (i >= Nin * C) return;
    int row = i / C, c = i - row * C;
    atomicMax(&enc[(size_t)pm[row] * C + c], enc_f32(fin[i]));
}

__global__ void pool_dec(unsigned* __restrict__ buf, int n)
{
    int i = blockIdx.x * blockDim.x + threadIdx.x;
    if (i >= n) return;
    unsigned u = buf[i];
    buf[i] = (u & 0x80000000u) ? (u ^ 0x80000000u) : ~u;  // bits of decoded float
}

extern "C" void kernel_launch(void* const* d_in, const int* in_sizes, int n_in,
                              void* d_out, int out_size, void* d_ws, size_t ws_size,
                              hipStream_t stream)
{
    // inputs: nbr0,pool0,nbr1,pool1,...,nbr5,pool5,nbr6 (0..12), w0a..w6b (13..26),
    //         features (27), coors (28), batch_size (29)
    const int* nbr[7];
    const int* pm[6];
    int Ns[7];
    {
        int idx = 0;
        for (int l = 0; l < 7; ++l) {
            nbr[l] = (const int*)d_in[idx];
            Ns[l]  = in_sizes[idx] / KTAPS;
            ++idx;
            if (l < 6) { pm[l] = (const int*)d_in[idx]; ++idx; }
        }
    }
    const float* w[14];
    for (int i = 0; i < 14; ++i) w[i] = (const float*)d_in[13 + i];
    const float* feat = (const float*)d_in[27];

    static const int CI[14] = {3,64, 64,96, 96,128, 128,160, 160,192, 192,224, 224,256};
    static const int CO[14] = {64,64, 96,96, 128,128, 160,160, 192,192, 224,224, 256,256};

    // two ping-pong feature buffers in d_ws
    size_t maxE = 0;
    for (int l = 0; l < 7; ++l) {
        size_t a = (size_t)Ns[l] * CO[2*l];
        size_t b = (size_t)Ns[l] * CO[2*l+1];
        if (a > maxE) maxE = a;
        if (b > maxE) maxE = b;
    }
    maxE = (maxE + 3) & ~(size_t)3;
    float* A = (float*)d_ws;
    float* B = A + maxE;

    const float* cur = feat;
    for (int l = 0; l < 7; ++l) {
        int N = Ns[l];
        // conv a
        float* t1 = (cur == (const float*)A) ? B : A;
        {
            int Cin = CI[2*l], Cout = CO[2*l];
            dim3 g((N + 31) / 32, (Cout + 63) / 64);
            subm_conv<<<g, 256, 0, stream>>>(cur, nbr[l], w[2*l], t1, N, Cin, Cout);
        }
        // conv b
        float* t2 = (l == 6) ? (float*)d_out : ((t1 == A) ? B : A);
        {
            int Cin = CI[2*l+1], Cout = CO[2*l+1];
            dim3 g((N + 31) / 32, (Cout + 63) / 64);
            subm_conv<<<g, 256, 0, stream>>>(t1, nbr[l], w[2*l+1], t2, N, Cin, Cout);
        }
        cur = t2;
        // pool
        if (l < 6) {
            int C    = CO[2*l+1];
            int Nout = Ns[l+1];
            float* t3 = (t2 == A) ? B : A;
            hipMemsetAsync(t3, 0, (size_t)Nout * C * sizeof(float), stream);
            int tot = N * C;
            pool_max<<<(tot + 255) / 256, 256, 0, stream>>>(cur, pm[l], (unsigned*)t3, N, C);
            int tot2 = Nout * C;
            pool_dec<<<(tot2 + 255) / 256, 256, 0, stream>>>((unsigned*)t3, tot2);
            cur = t3;
        }
    }
}

// Round 2
// 1347.780 us; speedup vs baseline: 6.3797x; 6.3797x over previous
//
#include <hip/hip_runtime.h>
#include <stddef.h>

#define KTAPS 125

// SubM conv, tap-split: out[n,co] += sum_{k in group} sum_ci fin[nbr[n,k],ci] * w[k,ci,co]
// Block: 256 threads, 64 rows x 64 cols, 4x4 acc per thread, ci chunks of 16.
// Grid: (row_tiles, col_tiles, TS tap groups). TS>1 -> atomicAdd into zeroed fout.
__global__ __launch_bounds__(256) void subm_conv(
    const float* __restrict__ fin, const int* __restrict__ nbr,
    const float* __restrict__ w, float* __restrict__ fout,
    int N, int Cin, int Cout, int TS)
{
    const int BM = 64, BN = 64, CK = 16;
    __shared__ int   nb[BM];
    __shared__ float G[CK][BM + 4];   // stride 68 words: stage-write 2-way (free), read 16B-aligned
    __shared__ float W[CK][BN];

    int tid  = threadIdx.x;
    int row0 = blockIdx.x * BM;
    int co0  = blockIdx.y * BN;
    int g    = blockIdx.z;
    int k0   = (g * KTAPS) / TS;
    int k1   = ((g + 1) * KTAPS) / TS;

    int r4 = (tid >> 4) * 4;   // 0..60
    int c4 = (tid & 15) * 4;   // 0..60

    float acc[4][4] = {};
    bool any = false;

    for (int k = k0; k < k1; ++k) {
        int v = -1;
        if (tid < BM) {
            int r = row0 + tid;
            v = (r < N) ? nbr[(size_t)r * KTAPS + k] : -1;
            nb[tid] = v;
        }
        if (!__syncthreads_or(v >= 0)) continue;
        any = true;

        for (int ci0 = 0; ci0 < Cin; ci0 += CK) {
            // stage G: 64 rows x 16 ci; tid-fast over ci -> 64B coalesced per row
            #pragma unroll
            for (int rep = 0; rep < (BM * CK) / 256; ++rep) {
                int idx = tid + rep * 256;
                int ci  = idx & (CK - 1);
                int rr  = idx >> 4;
                int src = nb[rr];
                int c   = ci0 + ci;
                float val = (src >= 0 && c < Cin) ? fin[(size_t)src * Cin + c] : 0.f;
                G[ci][rr] = val;
            }
            // stage W: 16 ci x 64 co, one float4 per thread, coalesced over co
            {
                int ci = tid >> 4;
                int cc = (tid & 15) * 4;
                int c  = ci0 + ci;
                float4 wv = make_float4(0.f, 0.f, 0.f, 0.f);
                if (c < Cin && (co0 + cc) < Cout)
                    wv = *(const float4*)&w[((size_t)k * Cin + c) * Cout + co0 + cc];
                *(float4*)&W[ci][cc] = wv;
            }
            __syncthreads();
            #pragma unroll
            for (int ci = 0; ci < CK; ++ci) {
                float4 a = *(const float4*)&G[ci][r4];
                float4 b = *(const float4*)&W[ci][c4];
                acc[0][0] += a.x * b.x; acc[0][1] += a.x * b.y; acc[0][2] += a.x * b.z; acc[0][3] += a.x * b.w;
                acc[1][0] += a.y * b.x; acc[1][1] += a.y * b.y; acc[1][2] += a.y * b.z; acc[1][3] += a.y * b.w;
                acc[2][0] += a.z * b.x; acc[2][1] += a.z * b.y; acc[2][2] += a.z * b.z; acc[2][3] += a.z * b.w;
                acc[3][0] += a.w * b.x; acc[3][1] += a.w * b.y; acc[3][2] += a.w * b.z; acc[3][3] += a.w * b.w;
            }
            __syncthreads();
        }
    }

    if (!any) return;

    const float* av = &acc[0][0];
    if (TS > 1) {
        #pragma unroll
        for (int i = 0; i < 4; ++i) {
            int r = row0 + r4 + i;
            if (r >= N) continue;
            #pragma unroll
            for (int j = 0; j < 4; ++j) {
                int c = co0 + c4 + j;
                if (c < Cout) atomicAdd(&fout[(size_t)r * Cout + c], av[i * 4 + j]);
            }
        }
    } else {
        #pragma unroll
        for (int i = 0; i < 4; ++i) {
            int r = row0 + r4 + i;
            if (r >= N) continue;
            #pragma unroll
            for (int j = 0; j < 4; ++j) {
                int c = co0 + c4 + j;
                if (c < Cout) fout[(size_t)r * Cout + c] = av[i * 4 + j];
            }
        }
    }
}

// -------- segment max pool via order-invariant monotonic-uint atomicMax (exact)
__device__ __forceinline__ unsigned enc_f32(float f) {
    unsigned u = __float_as_uint(f);
    return (u & 0x80000000u) ? ~u : (u | 0x80000000u);
}

__global__ void pool_max(const float* __restrict__ fin, const int* __restrict__ pm,
                         unsigned* __restrict__ enc, int Nin, int C)
{
    int i = blockIdx.x * blockDim.x + threadIdx.x;
    if (i >= Nin * C) return;
    int row = i / C, c = i - row * C;
    atomicMax(&enc[(size_t)pm[row] * C + c], enc_f32(fin[i]));
}

__global__ void pool_dec(unsigned* __restrict__ buf, int n)
{
    int i = blockIdx.x * blockDim.x + threadIdx.x;
    if (i >= n) return;
    unsigned u = buf[i];
    buf[i] = (u & 0x80000000u) ? (u ^ 0x80000000u) : ~u;
}

static inline int pick_ts(int rt, int ct)
{
    int base = rt * ct;
    if (base >= 192) return 1;
    int ts = 768 / base;
    if (ts < 1) ts = 1;
    if (ts > KTAPS) ts = KTAPS;
    return ts;
}

extern "C" void kernel_launch(void* const* d_in, const int* in_sizes, int n_in,
                              void* d_out, int out_size, void* d_ws, size_t ws_size,
                              hipStream_t stream)
{
    // inputs: nbr0,pool0,nbr1,pool1,...,nbr5,pool5,nbr6 (0..12), w0a..w6b (13..26),
    //         features (27), coors (28), batch_size (29)
    const int* nbr[7];
    const int* pm[6];
    int Ns[7];
    {
        int idx = 0;
        for (int l = 0; l < 7; ++l) {
            nbr[l] = (const int*)d_in[idx];
            Ns[l]  = in_sizes[idx] / KTAPS;
            ++idx;
            if (l < 6) { pm[l] = (const int*)d_in[idx]; ++idx; }
        }
    }
    const float* w[14];
    for (int i = 0; i < 14; ++i) w[i] = (const float*)d_in[13 + i];
    const float* feat = (const float*)d_in[27];

    static const int CI[14] = {3,64, 64,96, 96,128, 128,160, 160,192, 192,224, 224,256};
    static const int CO[14] = {64,64, 96,96, 128,128, 160,160, 192,192, 224,224, 256,256};

    // two ping-pong feature buffers in d_ws
    size_t maxE = 0;
    for (int l = 0; l < 7; ++l) {
        size_t a = (size_t)Ns[l] * CO[2*l];
        size_t b = (size_t)Ns[l] * CO[2*l+1];
        if (a > maxE) maxE = a;
        if (b > maxE) maxE = b;
    }
    maxE = (maxE + 3) & ~(size_t)3;
    float* A = (float*)d_ws;
    float* B = A + maxE;

    const float* cur = feat;
    for (int l = 0; l < 7; ++l) {
        int N = Ns[l];
        // conv a
        float* t1 = (cur == (const float*)A) ? B : A;
        {
            int Cin = CI[2*l], Cout = CO[2*l];
            int rt = (N + 63) / 64, ct = (Cout + 63) / 64;
            int TS = pick_ts(rt, ct);
            if (TS > 1) hipMemsetAsync(t1, 0, (size_t)N * Cout * sizeof(float), stream);
            dim3 grd(rt, ct, TS);
            subm_conv<<<grd, 256, 0, stream>>>(cur, nbr[l], w[2*l], t1, N, Cin, Cout, TS);
        }
        // conv b
        float* t2 = (l == 6) ? (float*)d_out : ((t1 == A) ? B : A);
        {
            int Cin = CI[2*l+1], Cout = CO[2*l+1];
            int rt = (N + 63) / 64, ct = (Cout + 63) / 64;
            int TS = pick_ts(rt, ct);
            if (TS > 1) hipMemsetAsync(t2, 0, (size_t)N * Cout * sizeof(float), stream);
            dim3 grd(rt, ct, TS);
            subm_conv<<<grd, 256, 0, stream>>>(t1, nbr[l], w[2*l+1], t2, N, Cin, Cout, TS);
        }
        cur = t2;
        // pool
        if (l < 6) {
            int C    = CO[2*l+1];
            int Nout = Ns[l+1];
            float* t3 = (t2 == A) ? B : A;
            hipMemsetAsync(t3, 0, (size_t)Nout * C * sizeof(float), stream);
            int tot = N * C;
            pool_max<<<(tot + 255) / 256, 256, 0, stream>>>(cur, pm[l], (unsigned*)t3, N, C);
            int tot2 = Nout * C;
            pool_dec<<<(tot2 + 255) / 256, 256, 0, stream>>>((unsigned*)t3, tot2);
            cur = t3;
        }
    }
}

// Round 3
// 1184.793 us; speedup vs baseline: 7.2574x; 1.1376x over previous
//
#include <hip/hip_runtime.h>
#include <stddef.h>

#define KTAPS 125

typedef _Float16 f16x8 __attribute__((ext_vector_type(8)));
typedef _Float16 f16x4 __attribute__((ext_vector_type(4)));
typedef float    f32x4 __attribute__((ext_vector_type(4)));

// SubM conv via MFMA fp16 (fp32 accum). BM=64 rows, BN=Cout cols (ct=1).
// 4 waves: 2(M) x 2(N), per-wave 32 x BN/2. Tap-split TS over grid.y -> atomicAdd.
// LDS layouts are per-fragment: contiguous ds_read_b128 for A and B frags.
//   Ga[mt4][g4][r16][j8]  : A[r][k=g*8+j] of 64x32 chunk   (halfs)
//   Wl[g4][co BN][j8]     : B[k=g*8+j][co] of 32xBN chunk  (halfs)
// mask: per-tap 64-bit row-valid ballot -> skip staging+MFMA per 16-row m-tile.
template<int NT>
__global__ __launch_bounds__(256) void subm_mfma(
    const float* __restrict__ fin, const int* __restrict__ nbr,
    const float* __restrict__ w, float* __restrict__ fout,
    int N, int Cin, int TS, float inscale, float outscale)
{
    constexpr int BN = NT * 32;   // == Cout
    constexpr int WN = NT * 16;   // per-wave N
    const int BM = 64;

    __shared__ int nb[64];
    __shared__ unsigned long long smask;
    __shared__ _Float16 Ga[64 * 32];
    __shared__ _Float16 Wl[32 * BN];

    const int tid  = threadIdx.x;
    const int row0 = blockIdx.x * BM;
    const int ts   = blockIdx.y;
    const int k0   = (ts * KTAPS) / TS;
    const int k1   = ((ts + 1) * KTAPS) / TS;

    const int lane = tid & 63;
    const int wid  = tid >> 6;
    const int wy   = wid & 1;     // M half
    const int wx   = wid >> 1;    // N half
    const int lr   = lane & 15;
    const int lg   = lane >> 4;

    f32x4 acc[2][NT];
    #pragma unroll
    for (int a = 0; a < 2; ++a)
        #pragma unroll
        for (int b = 0; b < NT; ++b)
            acc[a][b] = (f32x4){0.f, 0.f, 0.f, 0.f};

    bool any_ever = false;

    for (int k = k0; k < k1; ++k) {
        int v = -1;
        if (tid < 64) {
            int r = row0 + tid;
            v = (r < N) ? nbr[(size_t)r * KTAPS + k] : -1;
            nb[tid] = v;
            unsigned long long m = __ballot(v >= 0);
            if (lane == 0) smask = m;
        }
        if (!__syncthreads_or(v >= 0)) continue;
        any_ever = true;
        const unsigned long long mask = smask;   // written pre-barrier by wave 0

        for (int ci0 = 0; ci0 < Cin; ci0 += 32) {
            // ---- stage G: 64 rows x 32 ci, float4 gather -> half4 (scaled)
            #pragma unroll
            for (int rep = 0; rep < 2; ++rep) {
                int u   = tid + rep * 256;
                int cq  = u & 7;          // ci quad
                int row = u >> 3;         // 0..63
                int mt  = row >> 4;
                if ((mask >> (mt * 16)) & 0xFFFFull) {
                    int src = nb[row];
                    int c   = ci0 + cq * 4;
                    float4 val = make_float4(0.f, 0.f, 0.f, 0.f);
                    if (src >= 0) {
                        const float* p = &fin[(size_t)src * Cin + c];
                        if (c + 3 < Cin) val = *(const float4*)p;
                        else {
                            if (c     < Cin) val.x = p[0];
                            if (c + 1 < Cin) val.y = p[1];
                            if (c + 2 < Cin) val.z = p[2];
                            if (c + 3 < Cin) val.w = p[3];
                        }
                    }
                    f16x4 h;
                    h[0] = (_Float16)(val.x * inscale);
                    h[1] = (_Float16)(val.y * inscale);
                    h[2] = (_Float16)(val.z * inscale);
                    h[3] = (_Float16)(val.w * inscale);
                    int g = cq >> 1, j4 = (cq & 1) * 4;
                    *(f16x4*)&Ga[((mt * 4 + g) * 16 + (row & 15)) * 8 + j4] = h;
                }
            }
            // ---- stage W: 32 ci x BN co; thread handles (g, co-pair), 8 float2 loads
            #pragma unroll
            for (int e = tid; e < 2 * BN; e += 256) {
                int g   = e / (BN / 2);
                int cop = e - g * (BN / 2);
                int co  = cop * 2;
                f16x8 w0, w1;
                #pragma unroll
                for (int j = 0; j < 8; ++j) {
                    int c = ci0 + g * 8 + j;
                    float2 t = make_float2(0.f, 0.f);
                    if (c < Cin) t = *(const float2*)&w[((size_t)k * Cin + c) * BN + co];
                    w0[j] = (_Float16)t.x;
                    w1[j] = (_Float16)t.y;
                }
                *(f16x8*)&Wl[((size_t)g * BN + co) * 8]     = w0;
                *(f16x8*)&Wl[((size_t)g * BN + co + 1) * 8] = w1;
            }
            __syncthreads();

            // ---- compute
            f16x8 bf[NT];
            #pragma unroll
            for (int nt = 0; nt < NT; ++nt)
                bf[nt] = *(const f16x8*)&Wl[(lg * BN + wx * WN + nt * 16 + lr) * 8];
            #pragma unroll
            for (int mt = 0; mt < 2; ++mt) {
                int gm = wy * 2 + mt;
                if ((mask >> (gm * 16)) & 0xFFFFull) {
                    f16x8 a = *(const f16x8*)&Ga[((gm * 4 + lg) * 16 + lr) * 8];
                    #pragma unroll
                    for (int nt = 0; nt < NT; ++nt)
                        acc[mt][nt] = __builtin_amdgcn_mfma_f32_16x16x32_f16(a, bf[nt], acc[mt][nt], 0, 0, 0);
                }
            }
            __syncthreads();
        }
    }

    if (!any_ever && TS > 1) return;

    #pragma unroll
    for (int mt = 0; mt < 2; ++mt) {
        int rbase = row0 + wy * 32 + mt * 16 + lg * 4;
        #pragma unroll
        for (int nt = 0; nt < NT; ++nt) {
            int col = wx * WN + nt * 16 + lr;
            #pragma unroll
            for (int i = 0; i < 4; ++i) {
                int r = rbase + i;
                if (r < N) {
                    float vo = acc[mt][nt][i] * outscale;
                    if (TS > 1) atomicAdd(&fout[(size_t)r * BN + col], vo);
                    else        fout[(size_t)r * BN + col] = vo;
                }
            }
        }
    }
}

// -------- segment max pool via order-invariant monotonic-uint atomicMax (exact)
__device__ __forceinline__ unsigned enc_f32(float f) {
    unsigned u = __float_as_uint(f);
    return (u & 0x80000000u) ? ~u : (u | 0x80000000u);
}

__global__ void pool_max(const float* __restrict__ fin, const int* __restrict__ pm,
                         unsigned* __restrict__ enc, int Nin, int C)
{
    int i = blockIdx.x * blockDim.x + threadIdx.x;
    if (i >= Nin * C) return;
    int row = i / C, c = i - row * C;
    atomicMax(&enc[(size_t)pm[row] * C + c], enc_f32(fin[i]));
}

__global__ void pool_dec(unsigned* __restrict__ buf, int n)
{
    int i = blockIdx.x * blockDim.x + threadIdx.x;
    if (i >= n) return;
    unsigned u = buf[i];
    buf[i] = (u & 0x80000000u) ? (u ^ 0x80000000u) : ~u;
}

static void launch_conv(int Cout, const float* fin, const int* nbr, const float* w,
                        float* fout, int N, int Cin, float insc, float outsc,
                        hipStream_t s)
{
    int rt = (N + 63) / 64;
    int TS = (384 + rt - 1) / rt;
    if (TS < 1) TS = 1;
    if (TS > KTAPS) TS = KTAPS;
    if (TS > 1) hipMemsetAsync(fout, 0, (size_t)N * Cout * sizeof(float), s);
    dim3 g(rt, TS);
    int NT = Cout / 32;
    switch (NT) {
        case 2: subm_mfma<2><<<g, 256, 0, s>>>(fin, nbr, w, fout, N, Cin, TS, insc, outsc); break;
        case 3: subm_mfma<3><<<g, 256, 0, s>>>(fin, nbr, w, fout, N, Cin, TS, insc, outsc); break;
        case 4: subm_mfma<4><<<g, 256, 0, s>>>(fin, nbr, w, fout, N, Cin, TS, insc, outsc); break;
        case 5: subm_mfma<5><<<g, 256, 0, s>>>(fin, nbr, w, fout, N, Cin, TS, insc, outsc); break;
        case 6: subm_mfma<6><<<g, 256, 0, s>>>(fin, nbr, w, fout, N, Cin, TS, insc, outsc); break;
        case 7: subm_mfma<7><<<g, 256, 0, s>>>(fin, nbr, w, fout, N, Cin, TS, insc, outsc); break;
        case 8: subm_mfma<8><<<g, 256, 0, s>>>(fin, nbr, w, fout, N, Cin, TS, insc, outsc); break;
    }
}

extern "C" void kernel_launch(void* const* d_in, const int* in_sizes, int n_in,
                              void* d_out, int out_size, void* d_ws, size_t ws_size,
                              hipStream_t stream)
{
    const int* nbr[7];
    const int* pm[6];
    int Ns[7];
    {
        int idx = 0;
        for (int l = 0; l < 7; ++l) {
            nbr[l] = (const int*)d_in[idx];
            Ns[l]  = in_sizes[idx] / KTAPS;
            ++idx;
            if (l < 6) { pm[l] = (const int*)d_in[idx]; ++idx; }
        }
    }
    const float* w[14];
    for (int i = 0; i < 14; ++i) w[i] = (const float*)d_in[13 + i];
    const float* feat = (const float*)d_in[27];

    static const int CI[14]  = {3,64, 64,96, 96,128, 128,160, 160,192, 192,224, 224,256};
    static const int CO[14]  = {64,64, 96,96, 128,128, 160,160, 192,192, 224,224, 256,256};
    // exact power-of-2 feature pre-scales (keep fp16-staged values O(1)); sum = 17
    static const int KSH[14] = {0,3, 2,2, 1,1, 0,0, 0,1, 0,2, 2,3};
    const float finalScale = 1.0f / 131072.0f;   // 2^-17

    size_t maxE = 0;
    for (int l = 0; l < 7; ++l) {
        size_t a = (size_t)Ns[l] * CO[2*l];
        size_t b = (size_t)Ns[l] * CO[2*l+1];
        if (a > maxE) maxE = a;
        if (b > maxE) maxE = b;
    }
    maxE = (maxE + 3) & ~(size_t)3;
    float* A = (float*)d_ws;
    float* B = A + maxE;

    const float* cur = feat;
    for (int l = 0; l < 7; ++l) {
        int N = Ns[l];
        float* t1 = (cur == (const float*)A) ? B : A;
        launch_conv(CO[2*l], cur, nbr[l], w[2*l], t1, N, CI[2*l],
                    (float)(1 << KSH[2*l]), 1.f, stream);
        float* t2 = (l == 6) ? (float*)d_out : ((t1 == A) ? B : A);
        launch_conv(CO[2*l+1], t1, nbr[l], w[2*l+1], t2, N, CI[2*l+1],
                    (float)(1 << KSH[2*l+1]), (l == 6) ? finalScale : 1.f, stream);
        cur = t2;
        if (l < 6) {
            int C    = CO[2*l+1];
            int Nout = Ns[l+1];
            float* t3 = (t2 == A) ? B : A;
            hipMemsetAsync(t3, 0, (size_t)Nout * C * sizeof(float), stream);
            int tot = N * C;
            pool_max<<<(tot + 255) / 256, 256, 0, stream>>>(cur, pm[l], (unsigned*)t3, N, C);
            int tot2 = Nout * C;
            pool_dec<<<(tot2 + 255) / 256, 256, 0, stream>>>((unsigned*)t3, tot2);
            cur = t3;
        }
    }
}

// Round 5
// 438.803 us; speedup vs baseline: 19.5953x; 2.7001x over previous
//
#include <hip/hip_runtime.h>
#include <stddef.h>
#include <stdint.h>

#define KTAPS 125

typedef _Float16 f16x8 __attribute__((ext_vector_type(8)));
typedef float    f32x4 __attribute__((ext_vector_type(4)));

__device__ __forceinline__ void gload16(const void* g, void* l) {
    __builtin_amdgcn_global_load_lds(
        (const __attribute__((address_space(1))) void*)g,
        (__attribute__((address_space(3))) void*)l, 16, 0, 0);
}

// ---------------- conv: fp16 MFMA, double-buffered global_load_lds pipeline ----------------
// Block 256 = 4 waves; wave w owns m-tile w (16 rows) x ALL BN cols (NF = BN/16 fragments).
// LDS granule map (16B): Ga granule = wid*64 + lane  (A-frag = own granule; (l&~15)+(l&15)=l)
//                        Wl granule = kg*BN + co     (B-frag fragment order)
// Grid: (rowtiles, TS tap-splits, CS ci-splits); partial sums combined via fp32 atomicAdd.
template<int NT>
__global__ __launch_bounds__(256) void subm_mfma(
    const _Float16* __restrict__ finh, const int* __restrict__ nbr,
    const _Float16* __restrict__ wt, float* __restrict__ fout,
    int N, int CinP, int TS, int CS, float outscale)
{
    constexpr int BN = NT * 32;
    constexpr int NF = NT * 2;     // 16-col fragments per wave (all BN cols)
    __shared__ int       nbs[16][64];
    __shared__ unsigned  msk[16][2];
    __shared__ unsigned char vtl[16];
    __shared__ _Float16  Ga[2][64 * 32];
    __shared__ _Float16  Wl[2][32 * BN];

    const int tid  = threadIdx.x;
    const int lane = tid & 63;
    const int wid  = tid >> 6;
    const int row0 = blockIdx.x * 64;
    const int ts   = blockIdx.y;
    const int cs   = blockIdx.z;
    const int k0   = (ts * KTAPS) / TS;
    const int k1   = ((ts + 1) * KTAPS) / TS;
    const int KR   = k1 - k0;
    const int CC   = CinP >> 5;
    const int cc0  = (cs * CC) / CS;
    const int cc1  = ((cs + 1) * CC) / CS;

    // ---- neighbor slab for this block's 64 rows x KR taps
    #pragma unroll
    for (int p = 0; p < 4; ++p) {
        int e = tid + p * 256;
        if (e < KR * 64) {
            int j = e >> 6, r = e & 63;
            int gr = row0 + r;
            nbs[j][r] = (gr < N) ? nbr[(size_t)gr * KTAPS + k0 + j] : -1;
        }
    }
    __syncthreads();
    for (int j = wid; j < KR; j += 4) {
        unsigned long long m = __ballot(nbs[j][lane] >= 0);
        if (lane == 0) { msk[j][0] = (unsigned)m; msk[j][1] = (unsigned)(m >> 32); }
    }
    __syncthreads();
    int VC = 0;
    for (int j = 0; j < KR; ++j)
        if (msk[j][0] | msk[j][1]) { vtl[VC] = (unsigned char)j; ++VC; }
    if (VC == 0) return;

    const int r15 = lane & 15, g4 = lane >> 4;
    const int myrow = wid * 16 + r15;

    f32x4 acc[NF];
    #pragma unroll
    for (int n = 0; n < NF; ++n) acc[n] = (f32x4){0.f, 0.f, 0.f, 0.f};
    unsigned um = 0;

    auto STAGE = [&](int i, int c, int buf) {
        int j = vtl[i];
        int nb = nbs[j][myrow];
        int src = (nb < 0) ? N : nb;                       // row N = zero row
        gload16(finh + (size_t)src * CinP + c * 32 + g4 * 8,
                &Ga[buf][(size_t)wid * 512]);
        int k = k0 + j;
        const _Float16* ws = wt + ((size_t)k * CC + c) * (32 * (size_t)BN);
        #pragma unroll
        for (int p = 0; p < (BN + 63) / 64; ++p) {
            int gI = p * 256 + tid;
            if (gI < 4 * BN)
                gload16(ws + (size_t)gI * 8, &Wl[buf][((size_t)p * 256 + wid * 64) * 8]);
        }
    };

    auto COMPUTE = [&](int i, int buf) {
        int j = vtl[i];
        unsigned mw = (msk[j][wid >> 1] >> ((wid & 1) * 16)) & 0xFFFFu;
        mw = __builtin_amdgcn_readfirstlane(mw);
        if (mw) {
            um |= mw;
            f16x8 a = *(const f16x8*)&Ga[buf][(size_t)tid * 8];
            #pragma unroll
            for (int n = 0; n < NF; ++n) {
                f16x8 b = *(const f16x8*)&Wl[buf][((size_t)g4 * BN + n * 16 + r15) * 8];
                acc[n] = __builtin_amdgcn_mfma_f32_16x16x32_f16(a, b, acc[n], 0, 0, 0);
            }
        }
    };

    // ---- pipelined loop: 1 barrier per step
    int i = 0, c = cc0, buf = 0;
    STAGE(0, cc0, 0);
    while (true) {
        __syncthreads();                       // buf staged; buf^1 readers done
        int ni = i, nc = c + 1;
        if (nc == cc1) { ni = i + 1; nc = cc0; }
        if (ni < VC) STAGE(ni, nc, buf ^ 1);
        COMPUTE(i, buf);
        i = ni; c = nc; buf ^= 1;
        if (i >= VC) break;
    }

    if (!__builtin_amdgcn_readfirstlane(um)) return;
    const bool atom = (TS * CS) > 1;
    #pragma unroll
    for (int n = 0; n < NF; ++n) {
        int col = n * 16 + r15;
        #pragma unroll
        for (int q = 0; q < 4; ++q) {
            int r = row0 + wid * 16 + g4 * 4 + q;
            if (r < N) {
                float v = acc[n][q] * outscale;
                if (atom) atomicAdd(&fout[(size_t)r * BN + col], v);
                else      fout[(size_t)r * BN + col] = v;
            }
        }
    }
}

// ---------------- per-level tap liveness flags (all 7 levels, one launch) ----------------
__global__ __launch_bounds__(256) void tap_flags(
    const int* n0, const int* n1, const int* n2, const int* n3,
    const int* n4, const int* n5, const int* n6,
    int N0, int N1, int N2, int N3, int N4, int N5, int N6,
    unsigned* __restrict__ flags)
{
    int l = blockIdx.y, k = blockIdx.x;
    const int* nb; int N;
    switch (l) {
        case 0: nb = n0; N = N0; break;  case 1: nb = n1; N = N1; break;
        case 2: nb = n2; N = N2; break;  case 3: nb = n3; N = N3; break;
        case 4: nb = n4; N = N4; break;  case 5: nb = n5; N = N5; break;
        default: nb = n6; N = N6; break;
    }
    bool any = false;
    for (int r = threadIdx.x; r < N; r += 256) any |= (nb[(size_t)r * KTAPS + k] >= 0);
    bool a = __syncthreads_or(any);
    if (threadIdx.x == 0) flags[l * KTAPS + k] = a ? 1u : 0u;
}

// ---------------- weight convert+transpose to MFMA fragment order (a and b fused) --------
__global__ __launch_bounds__(256) void cvt_weights(
    const float* __restrict__ wa, const float* __restrict__ wb,
    _Float16* __restrict__ ta, _Float16* __restrict__ tb,
    const unsigned* __restrict__ flags,
    int CinA, int CCa, int CoutA, int splitA,
    int CinB, int CCb, int CoutB)
{
    int k = blockIdx.x;
    if (!flags[k]) return;
    int by = blockIdx.y;
    const float* w; _Float16* t; int Cin, CC, Cout, cc, c0;
    if (by < splitA) { w = wa; t = ta; Cin = CinA; CC = CCa; Cout = CoutA;
                       cc = by / (CoutA / 32); c0 = (by % (CoutA / 32)) * 32; }
    else { by -= splitA; w = wb; t = tb; Cin = CinB; CC = CCb; Cout = CoutB;
           cc = by / (CoutB / 32); c0 = (by % (CoutB / 32)) * 32; }

    __shared__ float T[32][33];
    int tid = threadIdx.x;
    #pragma unroll
    for (int p = 0; p < 4; ++p) {
        int e = tid + p * 256;
        int r = e >> 5, cl = e & 31;
        int ci = cc * 32 + r;
        T[r][cl] = (ci < Cin) ? w[((size_t)k * Cin + ci) * Cout + c0 + cl] : 0.f;
    }
    __syncthreads();
    if (tid < 128) {
        int g = tid >> 5, co = tid & 31;
        f16x8 h;
        #pragma unroll
        for (int j = 0; j < 8; ++j) h[j] = (_Float16)T[g * 8 + j][co];
        *(f16x8*)&t[((size_t)k * CC + cc) * (32 * (size_t)Cout) + ((size_t)g * Cout + c0 + co) * 8] = h;
    }
}

// ---------------- init: zero F + ENC, build padded fp16 input features -------------------
__global__ __launch_bounds__(256) void init_all(
    const float* __restrict__ feat, _Float16* __restrict__ H,
    float* __restrict__ F, unsigned* __restrict__ ENC,
    int N0, int nF, int nE)
{
    int i = blockIdx.x * 256 + threadIdx.x;
    if (i < nF) F[i] = 0.f;
    if (i < nE) ENC[i] = 0u;
    int nH = (N0 + 1) * 32;
    if (i < nH) {
        int r = i >> 5, cl = i & 31;
        H[i] = (r < N0 && cl < 3) ? (_Float16)feat[r * 3 + cl] : (_Float16)0.f;
    }
}

// ---------------- fp32 -> fp16 feature convert (zeroes source for reuse) -----------------
__global__ __launch_bounds__(256) void cvt_feat(
    float* __restrict__ F, _Float16* __restrict__ H, int N, int C, float scale)
{
    int i = blockIdx.x * 256 + threadIdx.x;
    if (i < N * C) { H[i] = (_Float16)(F[i] * scale); F[i] = 0.f; }
    else if (i < (N + 1) * C) H[i] = (_Float16)0.f;
}

// ---------------- segment max pool (monotonic-uint atomicMax; zeroes source) -------------
__device__ __forceinline__ unsigned enc_f32(float f) {
    unsigned u = __float_as_uint(f);
    return (u & 0x80000000u) ? ~u : (u | 0x80000000u);
}

__global__ __launch_bounds__(256) void pool_max(
    float* __restrict__ F, const int* __restrict__ pm,
    unsigned* __restrict__ ENC, int Nin, int C)
{
    int i = blockIdx.x * 256 + threadIdx.x;
    if (i >= Nin * C) return;
    int r = i / C, cl = i - r * C;
    atomicMax(&ENC[(size_t)pm[r] * C + cl], enc_f32(F[i]));
    F[i] = 0.f;
}

__global__ __launch_bounds__(256) void pool_dec(
    unsigned* __restrict__ ENC, _Float16* __restrict__ H, int Nout, int C, float scale)
{
    int i = blockIdx.x * 256 + threadIdx.x;
    if (i < Nout * C) {
        unsigned u = ENC[i];
        float f = __uint_as_float((u & 0x80000000u) ? (u ^ 0x80000000u) : ~u);
        H[i] = (_Float16)(f * scale);
        ENC[i] = 0u;
    } else if (i < (Nout + 1) * C) {
        H[i] = (_Float16)0.f;
    }
}

// ---------------- host ----------------
static void launch_conv(const _Float16* fin, const int* nbr, const _Float16* wt, float* fout,
                        int N, int CinP, int Cout, float outscale, hipStream_t s)
{
    int rt = (N + 63) / 64;
    int TS = (512 + rt - 1) / rt;
    if (TS < 8) TS = 8;
    if (TS > KTAPS) TS = KTAPS;
    int CC = CinP / 32;
    int CS = (rt == 1 && TS == KTAPS) ? CC : 1;
    dim3 g(rt, TS, CS);
    switch (Cout / 32) {
        case 2: subm_mfma<2><<<g, 256, 0, s>>>(fin, nbr, wt, fout, N, CinP, TS, CS, outscale); break;
        case 3: subm_mfma<3><<<g, 256, 0, s>>>(fin, nbr, wt, fout, N, CinP, TS, CS, outscale); break;
        case 4: subm_mfma<4><<<g, 256, 0, s>>>(fin, nbr, wt, fout, N, CinP, TS, CS, outscale); break;
        case 5: subm_mfma<5><<<g, 256, 0, s>>>(fin, nbr, wt, fout, N, CinP, TS, CS, outscale); break;
        case 6: subm_mfma<6><<<g, 256, 0, s>>>(fin, nbr, wt, fout, N, CinP, TS, CS, outscale); break;
        case 7: subm_mfma<7><<<g, 256, 0, s>>>(fin, nbr, wt, fout, N, CinP, TS, CS, outscale); break;
        case 8: subm_mfma<8><<<g, 256, 0, s>>>(fin, nbr, wt, fout, N, CinP, TS, CS, outscale); break;
    }
}

extern "C" void kernel_launch(void* const* d_in, const int* in_sizes, int n_in,
                              void* d_out, int out_size, void* d_ws, size_t ws_size,
                              hipStream_t stream)
{
    const int* nbr[7]; const int* pm[6]; int Ns[7];
    {
        int idx = 0;
        for (int l = 0; l < 7; ++l) {
            nbr[l] = (const int*)d_in[idx];
            Ns[l]  = in_sizes[idx] / KTAPS;
            ++idx;
            if (l < 6) { pm[l] = (const int*)d_in[idx]; ++idx; }
        }
    }
    const float* w[14];
    for (int i = 0; i < 14; ++i) w[i] = (const float*)d_in[13 + i];
    const float* feat = (const float*)d_in[27];

    static const int CI[14]  = {3,64, 64,96, 96,128, 128,160, 160,192, 192,224, 224,256};
    static const int CO[14]  = {64,64, 96,96, 128,128, 160,160, 192,192, 224,224, 256,256};
    static const int KSH[14] = {0,3, 2,2, 1,1, 0,0, 0,1, 0,2, 2,3};   // sum = 17
    const float finalScale = 1.0f / 131072.0f;                        // 2^-17
    int CinP[14];
    for (int i = 0; i < 14; ++i) CinP[i] = (CI[i] < 32) ? 32 : CI[i];

    // ---- ws carve
    size_t maxF = 0, maxE = 0, maxHa = 0, maxHb = 0, maxWA = 0, maxWB = 0;
    for (int l = 0; l < 7; ++l) {
        size_t f = (size_t)Ns[l] * CO[2*l];
        if (f > maxF) maxF = f;
        if (l < 6) { size_t e = (size_t)Ns[l+1] * CO[2*l+1]; if (e > maxE) maxE = e; }
        size_t ha = (size_t)(Ns[l] + 1) * CinP[2*l];   if (ha > maxHa) maxHa = ha;
        size_t hb = (size_t)(Ns[l] + 1) * CinP[2*l+1]; if (hb > maxHb) maxHb = hb;
        size_t wa = (size_t)KTAPS * CinP[2*l] * CO[2*l];     if (wa > maxWA) maxWA = wa;
        size_t wb = (size_t)KTAPS * CinP[2*l+1] * CO[2*l+1]; if (wb > maxWB) maxWB = wb;
    }
    size_t off = 0;
    auto carve = [&](size_t bytes) -> void* {
        void* p = (char*)d_ws + off;
        off = (off + bytes + 255) & ~(size_t)255;
        return p;
    };
    float*     F    = (float*)carve(maxF * 4);
    unsigned*  ENC  = (unsigned*)carve(maxE * 4);
    _Float16*  Ha   = (_Float16*)carve(maxHa * 2);
    _Float16*  Hb   = (_Float16*)carve(maxHb * 2);
    _Float16*  wtA  = (_Float16*)carve(maxWA * 2);
    _Float16*  wtB  = (_Float16*)carve(maxWB * 2);
    unsigned*  flags= (unsigned*)carve(7 * KTAPS * 4);

    hipMemsetAsync(d_out, 0, (size_t)out_size * sizeof(float), stream);

    {
        int nInit = (int)maxF;
        if ((int)maxE > nInit) nInit = (int)maxE;
        int nH = (Ns[0] + 1) * 32;
        if (nH > nInit) nInit = nH;
        init_all<<<(nInit + 255) / 256, 256, 0, stream>>>(feat, Ha, F, ENC, Ns[0], (int)maxF, (int)maxE);
    }
    tap_flags<<<dim3(KTAPS, 7), 256, 0, stream>>>(
        nbr[0], nbr[1], nbr[2], nbr[3], nbr[4], nbr[5], nbr[6],
        Ns[0], Ns[1], Ns[2], Ns[3], Ns[4], Ns[5], Ns[6], flags);

    for (int l = 0; l < 7; ++l) {
        int ia = 2 * l, ib = 2 * l + 1;
        int N = Ns[l];
        int splitA = (CinP[ia] / 32) * (CO[ia] / 32);
        int splitB = (CinP[ib] / 32) * (CO[ib] / 32);
        cvt_weights<<<dim3(KTAPS, splitA + splitB), 256, 0, stream>>>(
            w[ia], w[ib], wtA, wtB, flags + l * KTAPS,
            CI[ia], CinP[ia] / 32, CO[ia], splitA,
            CI[ib], CinP[ib] / 32, CO[ib]);

        launch_conv(Ha, nbr[l], wtA, F, N, CinP[ia], CO[ia], 1.f, stream);

        {
            int tot = (N + 1) * CO[ia];
            cvt_feat<<<(tot + 255) / 256, 256, 0, stream>>>(F, Hb, N, CO[ia], (float)(1 << KSH[ib]));
        }

        float* outb = (l == 6) ? (float*)d_out : F;
        launch_conv(Hb, nbr[l], wtB, outb, N, CinP[ib], CO[ib],
                    (l == 6) ? finalScale : 1.f, stream);

        if (l < 6) {
            int C = CO[ib], Nout = Ns[l + 1];
            int tot = N * C;
            pool_max<<<(tot + 255) / 256, 256, 0, stream>>>(F, pm[l], ENC, N, C);
            int tot2 = (Nout + 1) * C;
            pool_dec<<<(tot2 + 255) / 256, 256, 0, stream>>>(ENC, Ha, Nout, C,
                                                             (float)(1 << KSH[2 * l + 2]));
        }
    }
}

// Round 6
// 427.232 us; speedup vs baseline: 20.1260x; 1.0271x over previous
//
#include <hip/hip_runtime.h>
#include <stddef.h>
#include <stdint.h>

#define KTAPS 125

typedef _Float16 f16x8 __attribute__((ext_vector_type(8)));
typedef float    f32x4 __attribute__((ext_vector_type(4)));

// ---------------- conv: register-direct fp16 MFMA, no LDS staging, no inner barriers -----
// Block 256 = 4 waves as 2(M)x2(N): wave = 32 rows x BN/2 cols -> 2 m-frags x NT n-frags.
// A-frag: 16B/lane direct from features (row N = zero row). B-frag: 16B/lane direct from
// fragment-ordered fp16 weights. Per-wy valid-tap lists; umask skips zero rows at epilogue.
// Grid (rowtiles, TS tap-splits, CS ci-splits); partials combined via fp32 atomicAdd.
template<int NT, bool F32IN>
__global__ __launch_bounds__(256) void subm_mfma(
    const void* __restrict__ fin, const int* __restrict__ nbr,
    const _Float16* __restrict__ wt, float* __restrict__ fout,
    int N, int CinP, int TS, int CS, float inscale, float outscale)
{
    constexpr int BN = NT * 32;
    __shared__ int       nbs[16][64];
    __shared__ unsigned  msk[16][2];
    __shared__ unsigned char vtl[2][16];
    __shared__ int       vcs[2];

    const int tid  = threadIdx.x;
    const int lane = tid & 63;
    const int wid  = tid >> 6;
    const int wy   = wid & 1;
    const int wx   = wid >> 1;
    const int r15  = lane & 15;
    const int g4   = lane >> 4;
    const int row0 = blockIdx.x * 64;
    const int k0   = (blockIdx.y * KTAPS) / TS;
    const int k1   = ((blockIdx.y + 1) * KTAPS) / TS;
    const int KR   = k1 - k0;
    const int CC   = CinP >> 5;
    const int cc0  = (blockIdx.z * CC) / CS;
    const int cc1  = ((blockIdx.z + 1) * CC) / CS;

    #pragma unroll
    for (int p = 0; p < 4; ++p) {
        int e = tid + p * 256;
        if (e < KR * 64) {
            int j = e >> 6, r = e & 63;
            int gr = row0 + r;
            nbs[j][r] = (gr < N) ? nbr[(size_t)gr * KTAPS + k0 + j] : -1;
        }
    }
    __syncthreads();
    for (int j = wid; j < KR; j += 4) {
        unsigned long long m = __ballot(nbs[j][lane] >= 0);
        if (lane == 0) { msk[j][0] = (unsigned)m; msk[j][1] = (unsigned)(m >> 32); }
    }
    __syncthreads();
    if (wid < 2) {
        int c = 0;
        for (int j = 0; j < KR; ++j)
            if (msk[j][wid]) { if (lane == 0) vtl[wid][c] = (unsigned char)j; ++c; }
        if (lane == 0) vcs[wid] = c;
    }
    __syncthreads();
    const int VCw = vcs[wy];
    if (VCw == 0) return;

    unsigned um = 0;
    for (int t = 0; t < VCw; ++t) um |= msk[vtl[wy][t]][wy];

    f32x4 acc[2][NT];
    #pragma unroll
    for (int mt = 0; mt < 2; ++mt)
        #pragma unroll
        for (int nf = 0; nf < NT; ++nf)
            acc[mt][nf] = (f32x4){0.f, 0.f, 0.f, 0.f};

    const size_t wchunk = (size_t)32 * BN;                       // halfs per (k,cc) chunk
    const int    boffh  = (g4 * BN + wx * (NT * 16) + r15) * 8;  // + nf*128

    auto LOADA = [&](f16x8 (&a)[2], int j, int c) {
        #pragma unroll
        for (int mt = 0; mt < 2; ++mt) {
            int src = nbs[j][wy * 32 + mt * 16 + r15];
            if (src < 0) src = N;
            size_t base = (size_t)src * CinP + c * 32 + g4 * 8;
            if (F32IN) {
                const float* p = (const float*)fin + base;
                float4 v0 = *(const float4*)p;
                float4 v1 = *(const float4*)(p + 4);
                f16x8 h;
                h[0] = (_Float16)(v0.x * inscale); h[1] = (_Float16)(v0.y * inscale);
                h[2] = (_Float16)(v0.z * inscale); h[3] = (_Float16)(v0.w * inscale);
                h[4] = (_Float16)(v1.x * inscale); h[5] = (_Float16)(v1.y * inscale);
                h[6] = (_Float16)(v1.z * inscale); h[7] = (_Float16)(v1.w * inscale);
                a[mt] = h;
            } else {
                a[mt] = *(const f16x8*)((const _Float16*)fin + base);
            }
        }
    };
    auto LOADB = [&](f16x8 (&b)[NT], int j, int c) {
        const _Float16* base = wt + ((size_t)(k0 + j) * CC + c) * wchunk;
        #pragma unroll
        for (int nf = 0; nf < NT; ++nf)
            b[nf] = *(const f16x8*)&base[boffh + nf * 128];
    };
    auto MFMA = [&](f16x8 (&a)[2], f16x8 (&b)[NT]) {
        #pragma unroll
        for (int mt = 0; mt < 2; ++mt)
            #pragma unroll
            for (int nf = 0; nf < NT; ++nf)
                acc[mt][nf] = __builtin_amdgcn_mfma_f32_16x16x32_f16(a[mt], b[nf], acc[mt][nf], 0, 0, 0);
    };

    f16x8 a0[2], b0[NT], a1[2], b1[NT];
    int i = 0, c = cc0;
    { int j = vtl[wy][0]; LOADA(a0, j, c); LOADB(b0, j, c); }
    while (true) {
        int ni = i, nc = c + 1; if (nc == cc1) { ni = i + 1; nc = cc0; }
        bool m1 = ni < VCw;
        if (m1) { int j = vtl[wy][ni]; LOADA(a1, j, nc); LOADB(b1, j, nc); }
        MFMA(a0, b0);
        if (!m1) break;
        i = ni; c = nc;
        ni = i; nc = c + 1; if (nc == cc1) { ni = i + 1; nc = cc0; }
        bool m2 = ni < VCw;
        if (m2) { int j = vtl[wy][ni]; LOADA(a0, j, nc); LOADB(b0, j, nc); }
        MFMA(a1, b1);
        if (!m2) break;
        i = ni; c = nc;
    }

    #pragma unroll
    for (int mt = 0; mt < 2; ++mt) {
        #pragma unroll
        for (int q = 0; q < 4; ++q) {
            int lr = mt * 16 + g4 * 4 + q;
            int gr = row0 + wy * 32 + lr;
            if (((um >> lr) & 1u) && gr < N) {
                #pragma unroll
                for (int nf = 0; nf < NT; ++nf) {
                    int col = wx * (NT * 16) + nf * 16 + r15;
                    atomicAdd(&fout[(size_t)gr * BN + col], acc[mt][nf][q] * outscale);
                }
            }
        }
    }
}

// ---------------- per-level tap liveness flags ----------------
__global__ __launch_bounds__(256) void tap_flags(
    const int* n0, const int* n1, const int* n2, const int* n3,
    const int* n4, const int* n5, const int* n6,
    int N0, int N1, int N2, int N3, int N4, int N5, int N6,
    unsigned* __restrict__ flags)
{
    int l = blockIdx.y, k = blockIdx.x;
    const int* nb; int N;
    switch (l) {
        case 0: nb = n0; N = N0; break;  case 1: nb = n1; N = N1; break;
        case 2: nb = n2; N = N2; break;  case 3: nb = n3; N = N3; break;
        case 4: nb = n4; N = N4; break;  case 5: nb = n5; N = N5; break;
        default: nb = n6; N = N6; break;
    }
    bool any = false;
    for (int r = threadIdx.x; r < N; r += 256) any |= (nb[(size_t)r * KTAPS + k] >= 0);
    bool a = __syncthreads_or(any);
    if (threadIdx.x == 0) flags[l * KTAPS + k] = a ? 1u : 0u;
}

// ---------------- weight convert+transpose to MFMA fragment order ----------------
__global__ __launch_bounds__(256) void cvt_weights(
    const float* __restrict__ wa, const float* __restrict__ wb,
    _Float16* __restrict__ ta, _Float16* __restrict__ tb,
    const unsigned* __restrict__ flags,
    int CinA, int CCa, int CoutA, int splitA,
    int CinB, int CCb, int CoutB)
{
    int k = blockIdx.x;
    if (!flags[k]) return;
    int by = blockIdx.y;
    const float* w; _Float16* t; int Cin, CC, Cout, cc, c0;
    if (by < splitA) { w = wa; t = ta; Cin = CinA; CC = CCa; Cout = CoutA;
                       cc = by / (CoutA / 32); c0 = (by % (CoutA / 32)) * 32; }
    else { by -= splitA; w = wb; t = tb; Cin = CinB; CC = CCb; Cout = CoutB;
           cc = by / (CoutB / 32); c0 = (by % (CoutB / 32)) * 32; }

    __shared__ float T[32][33];
    int tid = threadIdx.x;
    #pragma unroll
    for (int p = 0; p < 4; ++p) {
        int e = tid + p * 256;
        int r = e >> 5, cl = e & 31;
        int ci = cc * 32 + r;
        T[r][cl] = (ci < Cin) ? w[((size_t)k * Cin + ci) * Cout + c0 + cl] : 0.f;
    }
    __syncthreads();
    if (tid < 128) {
        int g = tid >> 5, co = tid & 31;
        f16x8 h;
        #pragma unroll
        for (int j = 0; j < 8; ++j) h[j] = (_Float16)T[g * 8 + j][co];
        *(f16x8*)&t[((size_t)k * CC + cc) * (32 * (size_t)Cout) + ((size_t)g * Cout + c0 + co) * 8] = h;
    }
}

// ---------------- init: zero Fa/Fb/ENC/d_out, build padded fp16 level-0 features ---------
__global__ __launch_bounds__(256) void init_all(
    const float* __restrict__ feat, _Float16* __restrict__ H,
    float* __restrict__ Fa, float* __restrict__ Fb,
    unsigned* __restrict__ ENC, float* __restrict__ dout,
    int N0, int nFa, int nFb, int nE, int nOut)
{
    int i = blockIdx.x * 256 + threadIdx.x;
    if (i < nFa) Fa[i] = 0.f;
    if (i < nFb) Fb[i] = 0.f;
    if (i < nE)  ENC[i] = 0u;
    if (i < nOut) dout[i] = 0.f;
    int nH = (N0 + 1) * 32;
    if (i < nH) {
        int r = i >> 5, cl = i & 31;
        H[i] = (r < N0 && cl < 3) ? (_Float16)feat[r * 3 + cl] : (_Float16)0.f;
    }
}

// ---------------- segment max pool (monotonic-uint atomicMax); also re-zeros Fa ----------
__device__ __forceinline__ unsigned enc_f32(float f) {
    unsigned u = __float_as_uint(f);
    return (u & 0x80000000u) ? ~u : (u | 0x80000000u);
}

__global__ __launch_bounds__(256) void pool_max(
    float* __restrict__ Fb, const int* __restrict__ pm,
    unsigned* __restrict__ ENC, float* __restrict__ Fa,
    int Nin, int C, int nzero)
{
    int i = blockIdx.x * 256 + threadIdx.x;
    if (i < Nin * C) {
        int r = i / C, cl = i - r * C;
        atomicMax(&ENC[(size_t)pm[r] * C + cl], enc_f32(Fb[i]));
        Fb[i] = 0.f;
    }
    if (i < nzero) Fa[i] = 0.f;
}

__global__ __launch_bounds__(256) void pool_dec(
    unsigned* __restrict__ ENC, _Float16* __restrict__ H, int Nout, int C, float scale)
{
    int i = blockIdx.x * 256 + threadIdx.x;
    if (i < Nout * C) {
        unsigned u = ENC[i];
        float f = __uint_as_float((u & 0x80000000u) ? (u ^ 0x80000000u) : ~u);
        H[i] = (_Float16)(f * scale);
        ENC[i] = 0u;
    } else if (i < (Nout + 1) * C) {
        H[i] = (_Float16)0.f;
    }
}

// ---------------- host ----------------
template<bool F32>
static void conv_dispatch(int NT, dim3 g, hipStream_t s, const void* fin, const int* nbr,
                          const _Float16* wt, float* fout, int N, int CinP, int TS, int CS,
                          float insc, float outsc)
{
    switch (NT) {
        case 2: subm_mfma<2,F32><<<g,256,0,s>>>(fin,nbr,wt,fout,N,CinP,TS,CS,insc,outsc); break;
        case 3: subm_mfma<3,F32><<<g,256,0,s>>>(fin,nbr,wt,fout,N,CinP,TS,CS,insc,outsc); break;
        case 4: subm_mfma<4,F32><<<g,256,0,s>>>(fin,nbr,wt,fout,N,CinP,TS,CS,insc,outsc); break;
        case 5: subm_mfma<5,F32><<<g,256,0,s>>>(fin,nbr,wt,fout,N,CinP,TS,CS,insc,outsc); break;
        case 6: subm_mfma<6,F32><<<g,256,0,s>>>(fin,nbr,wt,fout,N,CinP,TS,CS,insc,outsc); break;
        case 7: subm_mfma<7,F32><<<g,256,0,s>>>(fin,nbr,wt,fout,N,CinP,TS,CS,insc,outsc); break;
        case 8: subm_mfma<8,F32><<<g,256,0,s>>>(fin,nbr,wt,fout,N,CinP,TS,CS,insc,outsc); break;
    }
}

static void launch_conv(bool f32in, const void* fin, const int* nbr, const _Float16* wt,
                        float* fout, int N, int CinP, int Cout, float insc, float outsc,
                        hipStream_t s)
{
    int rt = (N + 63) / 64;
    int TS = (1536 + rt - 1) / rt;
    if (TS > KTAPS) TS = KTAPS;
    int CC = CinP / 32;
    int CS = 1;
    long blocks = (long)rt * TS;
    if (blocks < 1024) { CS = (int)((1536 + blocks - 1) / blocks); if (CS > CC) CS = CC; }
    dim3 g(rt, TS, CS);
    if (f32in) conv_dispatch<true >(Cout/32, g, s, fin, nbr, wt, fout, N, CinP, TS, CS, insc, outsc);
    else       conv_dispatch<false>(Cout/32, g, s, fin, nbr, wt, fout, N, CinP, TS, CS, insc, outsc);
}

extern "C" void kernel_launch(void* const* d_in, const int* in_sizes, int n_in,
                              void* d_out, int out_size, void* d_ws, size_t ws_size,
                              hipStream_t stream)
{
    const int* nbr[7]; const int* pm[6]; int Ns[7];
    {
        int idx = 0;
        for (int l = 0; l < 7; ++l) {
            nbr[l] = (const int*)d_in[idx];
            Ns[l]  = in_sizes[idx] / KTAPS;
            ++idx;
            if (l < 6) { pm[l] = (const int*)d_in[idx]; ++idx; }
        }
    }
    const float* w[14];
    for (int i = 0; i < 14; ++i) w[i] = (const float*)d_in[13 + i];
    const float* feat = (const float*)d_in[27];

    static const int CI[14]  = {3,64, 64,96, 96,128, 128,160, 160,192, 192,224, 224,256};
    static const int CO[14]  = {64,64, 96,96, 128,128, 160,160, 192,192, 224,224, 256,256};
    static const int KSH[14] = {0,3, 2,2, 1,1, 0,0, 0,1, 0,2, 2,3};   // cumulative sum = 17
    const float finalScale = 1.0f / 131072.0f;                        // 2^-17
    int CinP[14];
    for (int i = 0; i < 14; ++i) CinP[i] = (CI[i] < 32) ? 32 : CI[i];

    size_t maxFa = 0, maxFb = 0, maxE = 0, maxHa = 0, maxWA = 0, maxWB = 0;
    for (int l = 0; l < 7; ++l) {
        size_t fa = (size_t)(Ns[l] + 1) * CO[2*l];   if (fa > maxFa) maxFa = fa;
        size_t fb = (size_t)(Ns[l] + 1) * CO[2*l+1]; if (fb > maxFb) maxFb = fb;
        if (l < 6) { size_t e = (size_t)Ns[l+1] * CO[2*l+1]; if (e > maxE) maxE = e; }
        size_t ha = (size_t)(Ns[l] + 1) * CinP[2*l]; if (ha > maxHa) maxHa = ha;
        size_t wa = (size_t)KTAPS * CinP[2*l] * CO[2*l];     if (wa > maxWA) maxWA = wa;
        size_t wb = (size_t)KTAPS * CinP[2*l+1] * CO[2*l+1]; if (wb > maxWB) maxWB = wb;
    }
    size_t off = 0;
    auto carve = [&](size_t bytes) -> void* {
        void* p = (char*)d_ws + off;
        off = (off + bytes + 255) & ~(size_t)255;
        return p;
    };
    float*     Fa   = (float*)carve(maxFa * 4);
    float*     Fb   = (float*)carve(maxFb * 4);
    unsigned*  ENC  = (unsigned*)carve(maxE * 4);
    _Float16*  Ha   = (_Float16*)carve(maxHa * 2);
    _Float16*  wtA  = (_Float16*)carve(maxWA * 2);
    _Float16*  wtB  = (_Float16*)carve(maxWB * 2);
    unsigned*  flags= (unsigned*)carve(7 * KTAPS * 4);

    {
        int nMax = (int)maxFa;
        if ((int)maxFb > nMax) nMax = (int)maxFb;
        if ((int)maxE  > nMax) nMax = (int)maxE;
        int nH = (Ns[0] + 1) * 32;
        if (nH > nMax) nMax = nH;
        if (out_size > nMax) nMax = out_size;
        init_all<<<(nMax + 255) / 256, 256, 0, stream>>>(
            feat, Ha, Fa, Fb, ENC, (float*)d_out,
            Ns[0], (int)maxFa, (int)maxFb, (int)maxE, out_size);
    }
    tap_flags<<<dim3(KTAPS, 7), 256, 0, stream>>>(
        nbr[0], nbr[1], nbr[2], nbr[3], nbr[4], nbr[5], nbr[6],
        Ns[0], Ns[1], Ns[2], Ns[3], Ns[4], Ns[5], Ns[6], flags);

    for (int l = 0; l < 7; ++l) {
        int ia = 2 * l, ib = 2 * l + 1;
        int N = Ns[l];
        int splitA = (CinP[ia] / 32) * (CO[ia] / 32);
        int splitB = (CinP[ib] / 32) * (CO[ib] / 32);
        cvt_weights<<<dim3(KTAPS, splitA + splitB), 256, 0, stream>>>(
            w[ia], w[ib], wtA, wtB, flags + l * KTAPS,
            CI[ia], CinP[ia] / 32, CO[ia], splitA,
            CI[ib], CinP[ib] / 32, CO[ib]);

        // conv a: fp16 features in (already scaled), fp32 atomic out
        launch_conv(false, Ha, nbr[l], wtA, Fa, N, CinP[ia], CO[ia], 1.f, 1.f, stream);

        // conv b: fp32 in (inline 2^KSH scale + cvt), fp32 atomic out
        float* outb = (l == 6) ? (float*)d_out : Fb;
        launch_conv(true, Fa, nbr[l], wtB, outb, N, CinP[ib], CO[ib],
                    (float)(1 << KSH[ib]), (l == 6) ? finalScale : 1.f, stream);

        if (l < 6) {
            int C = CO[ib], Nout = Ns[l + 1];
            // zero Fa for next layer's conv a while pooling
            int nzero = (Nout + 1) * CO[2 * l + 2];
            int tot = N * C; if (nzero > tot) tot = nzero;
            pool_max<<<(tot + 255) / 256, 256, 0, stream>>>(Fb, pm[l], ENC, Fa, N, C, nzero);
            int tot2 = (Nout + 1) * C;
            pool_dec<<<(tot2 + 255) / 256, 256, 0, stream>>>(ENC, Ha, Nout, C,
                                                             (float)(1 << KSH[2 * l + 2]));
        }
    }
}